// Round 4
// baseline (174.418 us; speedup 1.0000x reference)
//
#include <hip/hip_runtime.h>
#include <hip/hip_bf16.h>
#include <math.h>

typedef __attribute__((ext_vector_type(8))) short bf16x8;
typedef __attribute__((ext_vector_type(4))) float f32x4;
typedef __attribute__((ext_vector_type(2))) float f32x2;

__device__ __forceinline__ unsigned short f2bf(float f) {
    unsigned int u = __float_as_uint(f);
    unsigned int r = (u + 0x7FFFu + ((u >> 16) & 1u)) >> 16;
    return (unsigned short)r;
}
__device__ __forceinline__ unsigned int pk2bf(float lo, float hi) {
    unsigned int r;
    asm("v_cvt_pk_bf16_f32 %0, %1, %2" : "=v"(r) : "v"(lo), "v"(hi));
    return r;
}
__device__ __forceinline__ unsigned char f2fp8(float v) {
    int p = __builtin_amdgcn_cvt_pk_fp8_f32(v, v, 0, false);
    return (unsigned char)(p & 0xff);
}
__device__ __forceinline__ unsigned int pk4fp8(float a, float b, float c, float d) {
    int p = __builtin_amdgcn_cvt_pk_fp8_f32(a, b, 0, false);
    p = __builtin_amdgcn_cvt_pk_fp8_f32(c, d, p, true);
    return (unsigned int)p;
}
#if __has_builtin(__builtin_amdgcn_cvt_pk_f32_fp8)
__device__ __forceinline__ void fp8x8_add(uint2 u, float* a) {
    f32x2 p0 = __builtin_amdgcn_cvt_pk_f32_fp8((int)u.x, false);
    f32x2 p1 = __builtin_amdgcn_cvt_pk_f32_fp8((int)u.x, true);
    f32x2 p2 = __builtin_amdgcn_cvt_pk_f32_fp8((int)u.y, false);
    f32x2 p3 = __builtin_amdgcn_cvt_pk_f32_fp8((int)u.y, true);
    a[0] += p0.x; a[1] += p0.y; a[2] += p1.x; a[3] += p1.y;
    a[4] += p2.x; a[5] += p2.y; a[6] += p3.x; a[7] += p3.y;
}
__device__ __forceinline__ void fp8x4_add(unsigned int u, float* a) {
    f32x2 p0 = __builtin_amdgcn_cvt_pk_f32_fp8((int)u, false);
    f32x2 p1 = __builtin_amdgcn_cvt_pk_f32_fp8((int)u, true);
    a[0] += p0.x; a[1] += p0.y; a[2] += p1.x; a[3] += p1.y;
}
#else
__device__ __forceinline__ void fp8x8_add(uint2 u, float* a) {
    a[0] += __builtin_amdgcn_cvt_f32_fp8((int)u.x, 0);
    a[1] += __builtin_amdgcn_cvt_f32_fp8((int)u.x, 1);
    a[2] += __builtin_amdgcn_cvt_f32_fp8((int)u.x, 2);
    a[3] += __builtin_amdgcn_cvt_f32_fp8((int)u.x, 3);
    a[4] += __builtin_amdgcn_cvt_f32_fp8((int)u.y, 0);
    a[5] += __builtin_amdgcn_cvt_f32_fp8((int)u.y, 1);
    a[6] += __builtin_amdgcn_cvt_f32_fp8((int)u.y, 2);
    a[7] += __builtin_amdgcn_cvt_f32_fp8((int)u.y, 3);
}
__device__ __forceinline__ void fp8x4_add(unsigned int u, float* a) {
    a[0] += __builtin_amdgcn_cvt_f32_fp8((int)u, 0);
    a[1] += __builtin_amdgcn_cvt_f32_fp8((int)u, 1);
    a[2] += __builtin_amdgcn_cvt_f32_fp8((int)u, 2);
    a[3] += __builtin_amdgcn_cvt_f32_fp8((int)u, 3);
}
#endif
__device__ __forceinline__ float deg_dinv(int c) { return rsqrtf((float)c + 1.0f); }

__device__ __forceinline__ void load_lds16(const unsigned short* g, unsigned short* l) {
    __builtin_amdgcn_global_load_lds(
        (const __attribute__((address_space(1))) unsigned int*)g,
        (__attribute__((address_space(3))) unsigned int*)l, 16, 0, 0);
}
__device__ __forceinline__ void load_lds16_u8(const unsigned char* g, unsigned char* l) {
    __builtin_amdgcn_global_load_lds(
        (const __attribute__((address_space(1))) unsigned int*)g,
        (__attribute__((address_space(3))) unsigned int*)l, 16, 0, 0);
}

// ============ prep+fill: CSR fill | W1 -> bf16^T | W2 -> fp8^T | graph bounds ============
__global__ __launch_bounds__(256) void prepfill_kernel(const int* __restrict__ src,
                                                       const int* __restrict__ dst,
                                                       int* __restrict__ cnt,
                                                       int* __restrict__ csr,
                                                       const int* __restrict__ batch,
                                                       int* __restrict__ gstart,
                                                       const float* __restrict__ W1,
                                                       unsigned short* __restrict__ w1t,
                                                       const float* __restrict__ W2,
                                                       unsigned char* __restrict__ w2t8,
                                                       int N, int G, int E, int FB, int CWB) {
    int b = blockIdx.x;
    int tid = threadIdx.x;
    if (b < FB) {
        int e = (b * 256 + tid) * 4;
        if (e + 3 < E) {
            int4 d4 = *(const int4*)(dst + e);
            int4 s4 = *(const int4*)(src + e);
            int sl;
            sl = atomicAdd(&cnt[d4.x], 1); if (sl < 64) csr[(d4.x << 6) + sl] = s4.x;
            sl = atomicAdd(&cnt[d4.y], 1); if (sl < 64) csr[(d4.y << 6) + sl] = s4.y;
            sl = atomicAdd(&cnt[d4.z], 1); if (sl < 64) csr[(d4.z << 6) + sl] = s4.z;
            sl = atomicAdd(&cnt[d4.w], 1); if (sl < 64) csr[(d4.w << 6) + sl] = s4.w;
        } else {
            for (; e < E; e++) {
                int d = dst[e];
                int slot = atomicAdd(&cnt[d], 1);
                if (slot < 64) csr[(d << 6) + slot] = src[e];
            }
        }
        return;
    }
    b -= FB;
    if (b < CWB) {
        int idx = b * 256 + tid;
        if (idx < 256 * 256) {
            int m = idx >> 8, k = idx & 255;
            w1t[idx] = f2bf(W1[(size_t)k * 256 + m]);
        } else if (idx < 256 * 256 + 128 * 256) {
            int j = idx - 256 * 256;
            int m = j >> 8, k = j & 255;
            w2t8[j] = f2fp8(W2[(size_t)k * 128 + m]);
        }
        return;
    }
    b -= CWB;
    {
        int i = b * 256 + tid;
        if (i >= N) return;
        int bb = batch[i];
        if (i == 0) { for (int g = 0; g <= bb; g++) gstart[g] = 0; }
        else { int bp = batch[i - 1]; for (int g = bp + 1; g <= bb; g++) gstart[g] = i; }
        if (i == N - 1) { for (int g = bb + 1; g <= G; g++) gstart[g] = N; }
    }
}

// ---------------- layer-1 GEMM (f32 A direct, 128x128 tile), dinv-scaled fp8 out ----------------
__global__ __launch_bounds__(256) void gemm1_kernel(const float* __restrict__ x,
                                                    const unsigned short* __restrict__ Bt,
                                                    const int* __restrict__ cnt,
                                                    unsigned char* __restrict__ C8, int N) {
    __shared__ unsigned short As[128 * 32];   // 8 KB, swizzled chunks
    __shared__ unsigned short Bs[128 * 32];   // 8 KB, linear
    int gb = blockIdx.x;
    int bx = gb & 1, by = gb >> 1;
    const int K = 256;
    int tid = threadIdx.x;
    int wave = tid >> 6, lane = tid & 63;
    int quad = lane >> 4, m16 = lane & 15;
    int r0 = by * 128, c0 = bx * 128;
    int srow = lane >> 2;
    int skoff = (lane & 3) * 8;

    f32x4 acc[2][8];
#pragma unroll
    for (int rg = 0; rg < 2; rg++)
#pragma unroll
        for (int ct = 0; ct < 8; ct++) acc[rg][ct] = (f32x4){0.f, 0.f, 0.f, 0.f};

    int arow = tid >> 1, akh = tid & 1;
    int agrow = r0 + arow; if (agrow >= N) agrow = N - 1;
    const float* ap = x + (size_t)agrow * K + akh * 16;
    int asw = (arow >> 1) & 3;
    unsigned short* as0 = As + arow * 32 + ((((akh << 1) | 0) ^ asw) << 3);
    unsigned short* as1 = As + arow * 32 + ((((akh << 1) | 1) ^ asw) << 3);
    int rsw = (m16 >> 1) & 3;

    for (int kb = 0; kb < K; kb += 32) {
        float4 f0 = *(const float4*)(ap + kb);
        float4 f1 = *(const float4*)(ap + kb + 4);
        float4 f2 = *(const float4*)(ap + kb + 8);
        float4 f3 = *(const float4*)(ap + kb + 12);
        {
            int bcol = wave * 16 + srow;
            load_lds16(Bt + (size_t)(c0 + bcol) * K + kb + skoff, Bs + (wave * 16) * 32);
            load_lds16(Bt + (size_t)(c0 + 64 + bcol) * K + kb + skoff, Bs + (64 + wave * 16) * 32);
        }
        uint4 u0, u1;
        u0.x = pk2bf(f0.x, f0.y); u0.y = pk2bf(f0.z, f0.w);
        u0.z = pk2bf(f1.x, f1.y); u0.w = pk2bf(f1.z, f1.w);
        u1.x = pk2bf(f2.x, f2.y); u1.y = pk2bf(f2.z, f2.w);
        u1.z = pk2bf(f3.x, f3.y); u1.w = pk2bf(f3.z, f3.w);
        *(uint4*)as0 = u0;
        *(uint4*)as1 = u1;
        __syncthreads();
        bf16x8 af[2], bfr[8];
#pragma unroll
        for (int rg = 0; rg < 2; rg++)
            af[rg] = *(const bf16x8*)(As + (wave * 32 + rg * 16 + m16) * 32 + ((quad ^ rsw) << 3));
#pragma unroll
        for (int ct = 0; ct < 8; ct++)
            bfr[ct] = *(const bf16x8*)(Bs + (ct * 16 + m16) * 32 + (quad << 3));
#pragma unroll
        for (int rg = 0; rg < 2; rg++)
#pragma unroll
            for (int ct = 0; ct < 8; ct++)
                acc[rg][ct] = __builtin_amdgcn_mfma_f32_16x16x32_bf16(af[rg], bfr[ct], acc[rg][ct], 0, 0, 0);
        __syncthreads();
    }
    float di[2][4];
#pragma unroll
    for (int rg = 0; rg < 2; rg++)
#pragma unroll
        for (int r = 0; r < 4; r++) {
            int row = r0 + wave * 32 + rg * 16 + quad * 4 + r;
            di[rg][r] = (row < N) ? deg_dinv(cnt[row]) : 1.f;
        }
#pragma unroll
    for (int rg = 0; rg < 2; rg++) {
#pragma unroll
        for (int ct = 0; ct < 8; ct++) {
            int col = c0 + ct * 16 + m16;
#pragma unroll
            for (int r = 0; r < 4; r++) {
                int row = r0 + wave * 32 + rg * 16 + quad * 4 + r;
                if (row < N) C8[(size_t)row * 256 + col] = f2fp8(acc[rg][ct][r] * di[rg][r]);
            }
        }
    }
}

// ---------------- FUSED: layer-1 aggregate (gather256) + layer-2 GEMM ----------------
// 64-row tile per block, 512 threads. o1 never touches HBM.
// LDS swizzle (both tiles): 16B slot sr of row r stored at sr ^ (r&7)  [byte ^= (r&7)<<4]
__global__ __launch_bounds__(512) void l1agg_gemm2_kernel(const unsigned char* __restrict__ h8,
                                                          const int* __restrict__ csr,
                                                          const int* __restrict__ cnt,
                                                          const float* __restrict__ b1,
                                                          const unsigned char* __restrict__ w2t8,
                                                          unsigned char* __restrict__ t8,
                                                          int N) {
    __shared__ unsigned char As8[64 * 256];    // 16 KB o1 tile (fp8), swizzled
    __shared__ unsigned char Bs8[128 * 256];   // 32 KB W2^T (fp8), swizzled
    int tid = threadIdx.x;
    int wave = tid >> 6, lane = tid & 63;
    int r0 = blockIdx.x * 64;

    // ---- stage W2^T -> LDS (pre-swizzled SOURCE, linear dest) — overlaps gather ----
#pragma unroll
    for (int q = 0; q < 4; q++) {
        int s = q * 512 + wave * 64 + lane;       // 16B slot id
        int r = s >> 4, sr = s & 15;
        int gs = sr ^ (r & 7);
        load_lds16_u8(w2t8 + (size_t)r * 256 + gs * 16,
                      Bs8 + ((size_t)q * 512 + wave * 64) * 16);
    }

    // ---- gather phase: 16 half-wave streams, 4 nodes each ----
    int half_id = tid >> 5, hl = tid & 31;
    float4 bv0 = ((const float4*)b1)[hl * 2];
    float4 bv1 = ((const float4*)b1)[hl * 2 + 1];
    float bvf[8] = {bv0.x, bv0.y, bv0.z, bv0.w, bv1.x, bv1.y, bv1.z, bv1.w};
#pragma unroll
    for (int t = 0; t < 4; t++) {
        int nl = t * 16 + half_id;
        int n = r0 + nl;
        if (n < N) {
            int c = cnt[n];
            float dd = deg_dinv(c);
            if (c > 64) c = 64;
            int beg = n << 6, end = beg + c;
            uint2 uh = *(const uint2*)(h8 + (size_t)n * 256 + hl * 8);
            float a[8] = {0, 0, 0, 0, 0, 0, 0, 0};
            int j = beg;
            for (; j + 7 < end; j += 8) {
                int s0 = csr[j + 0], s1 = csr[j + 1], s2 = csr[j + 2], s3 = csr[j + 3];
                int s4 = csr[j + 4], s5 = csr[j + 5], s6 = csr[j + 6], s7 = csr[j + 7];
                uint2 u0 = *(const uint2*)(h8 + (size_t)s0 * 256 + hl * 8);
                uint2 u1 = *(const uint2*)(h8 + (size_t)s1 * 256 + hl * 8);
                uint2 u2 = *(const uint2*)(h8 + (size_t)s2 * 256 + hl * 8);
                uint2 u3 = *(const uint2*)(h8 + (size_t)s3 * 256 + hl * 8);
                uint2 u4 = *(const uint2*)(h8 + (size_t)s4 * 256 + hl * 8);
                uint2 u5 = *(const uint2*)(h8 + (size_t)s5 * 256 + hl * 8);
                uint2 u6 = *(const uint2*)(h8 + (size_t)s6 * 256 + hl * 8);
                uint2 u7 = *(const uint2*)(h8 + (size_t)s7 * 256 + hl * 8);
                fp8x8_add(u0, a); fp8x8_add(u1, a); fp8x8_add(u2, a); fp8x8_add(u3, a);
                fp8x8_add(u4, a); fp8x8_add(u5, a); fp8x8_add(u6, a); fp8x8_add(u7, a);
            }
            for (; j + 3 < end; j += 4) {
                int s0 = csr[j + 0], s1 = csr[j + 1], s2 = csr[j + 2], s3 = csr[j + 3];
                uint2 u0 = *(const uint2*)(h8 + (size_t)s0 * 256 + hl * 8);
                uint2 u1 = *(const uint2*)(h8 + (size_t)s1 * 256 + hl * 8);
                uint2 u2 = *(const uint2*)(h8 + (size_t)s2 * 256 + hl * 8);
                uint2 u3 = *(const uint2*)(h8 + (size_t)s3 * 256 + hl * 8);
                fp8x8_add(u0, a); fp8x8_add(u1, a); fp8x8_add(u2, a); fp8x8_add(u3, a);
            }
            for (; j < end; j++) {
                int s0 = csr[j];
                uint2 u0 = *(const uint2*)(h8 + (size_t)s0 * 256 + hl * 8);
                fp8x8_add(u0, a);
            }
            float self[8] = {0, 0, 0, 0, 0, 0, 0, 0};
            fp8x8_add(uh, self);
            float v[8];
#pragma unroll
            for (int i = 0; i < 8; i++) v[i] = fmaxf((a[i] + self[i]) * dd + bvf[i], 0.f);
            uint2 o;
            o.x = pk4fp8(v[0], v[1], v[2], v[3]);
            o.y = pk4fp8(v[4], v[5], v[6], v[7]);
            *(uint2*)(As8 + nl * 256 + ((hl * 8) ^ ((nl & 7) << 4))) = o;
        }
    }
    __syncthreads();

    // ---- GEMM phase: 64x128 tile, 8 waves as 2x4 grid of 32x32 sub-tiles ----
    int quad = lane >> 4, m16 = lane & 15;
    int wr = wave >> 2, wc = wave & 3;
    f32x4 acc[2][2];
#pragma unroll
    for (int rf = 0; rf < 2; rf++)
#pragma unroll
        for (int cf = 0; cf < 2; cf++) acc[rf][cf] = (f32x4){0.f, 0.f, 0.f, 0.f};
#pragma unroll
    for (int kb = 0; kb < 8; kb++) {
        int byt = kb * 32 + quad * 8;
        long af[2], bfr[2];
#pragma unroll
        for (int rf = 0; rf < 2; rf++) {
            int row = wr * 32 + rf * 16 + m16;
            af[rf] = *(const long*)(As8 + row * 256 + (byt ^ ((row & 7) << 4)));
        }
#pragma unroll
        for (int cf = 0; cf < 2; cf++) {
            int col = wc * 32 + cf * 16 + m16;
            bfr[cf] = *(const long*)(Bs8 + col * 256 + (byt ^ ((col & 7) << 4)));
        }
#pragma unroll
        for (int rf = 0; rf < 2; rf++)
#pragma unroll
            for (int cf = 0; cf < 2; cf++)
                acc[rf][cf] = __builtin_amdgcn_mfma_f32_16x16x32_fp8_fp8(af[rf], bfr[cf], acc[rf][cf], 0, 0, 0);
    }
    // dinv-prescaled epilogue for the next gather
#pragma unroll
    for (int rf = 0; rf < 2; rf++) {
        float di[4];
#pragma unroll
        for (int r = 0; r < 4; r++) {
            int row = r0 + wr * 32 + rf * 16 + quad * 4 + r;
            di[r] = (row < N) ? deg_dinv(cnt[row]) : 1.f;
        }
#pragma unroll
        for (int cf = 0; cf < 2; cf++) {
            int col = wc * 32 + cf * 16 + m16;
#pragma unroll
            for (int r = 0; r < 4; r++) {
                int row = r0 + wr * 32 + rf * 16 + quad * 4 + r;
                if (row < N) t8[(size_t)row * 128 + col] = f2fp8(acc[rf][cf][r] * di[r]);
            }
        }
    }
}

// ---------------- gather 128 ch, pre-scaled fp8 rows ----------------
__global__ __launch_bounds__(256) void gather128_kernel(const unsigned char* __restrict__ t8,
                                                        const int* __restrict__ csr,
                                                        const int* __restrict__ cnt,
                                                        const float* __restrict__ bias,
                                                        unsigned char* __restrict__ out2, int N) {
    int node = blockIdx.x * 4 + (threadIdx.x >> 6);
    if (node >= N) return;
    int lane = threadIdx.x & 63;
    int half = lane >> 5, hl = lane & 31;
    int beg = node << 6;
    int c = cnt[node];
    float dd = deg_dinv(c);
    if (c > 64) c = 64;
    int end = beg + c;
    unsigned int uh = *(const unsigned int*)(t8 + (size_t)node * 128 + hl * 4);
    float a[4] = {0, 0, 0, 0};
    int j = beg;
    for (; j + 15 < end; j += 16) {
        int s0 = csr[j + half],      s1 = csr[j + 2 + half];
        int s2 = csr[j + 4 + half],  s3 = csr[j + 6 + half];
        int s4 = csr[j + 8 + half],  s5 = csr[j + 10 + half];
        int s6 = csr[j + 12 + half], s7 = csr[j + 14 + half];
        unsigned int u0 = *(const unsigned int*)(t8 + (size_t)s0 * 128 + hl * 4);
        unsigned int u1 = *(const unsigned int*)(t8 + (size_t)s1 * 128 + hl * 4);
        unsigned int u2 = *(const unsigned int*)(t8 + (size_t)s2 * 128 + hl * 4);
        unsigned int u3 = *(const unsigned int*)(t8 + (size_t)s3 * 128 + hl * 4);
        unsigned int u4 = *(const unsigned int*)(t8 + (size_t)s4 * 128 + hl * 4);
        unsigned int u5 = *(const unsigned int*)(t8 + (size_t)s5 * 128 + hl * 4);
        unsigned int u6 = *(const unsigned int*)(t8 + (size_t)s6 * 128 + hl * 4);
        unsigned int u7 = *(const unsigned int*)(t8 + (size_t)s7 * 128 + hl * 4);
        fp8x4_add(u0, a); fp8x4_add(u1, a); fp8x4_add(u2, a); fp8x4_add(u3, a);
        fp8x4_add(u4, a); fp8x4_add(u5, a); fp8x4_add(u6, a); fp8x4_add(u7, a);
    }
    for (; j + 7 < end; j += 8) {
        int s0 = csr[j + half], s1 = csr[j + 2 + half];
        int s2 = csr[j + 4 + half], s3 = csr[j + 6 + half];
        unsigned int u0 = *(const unsigned int*)(t8 + (size_t)s0 * 128 + hl * 4);
        unsigned int u1 = *(const unsigned int*)(t8 + (size_t)s1 * 128 + hl * 4);
        unsigned int u2 = *(const unsigned int*)(t8 + (size_t)s2 * 128 + hl * 4);
        unsigned int u3 = *(const unsigned int*)(t8 + (size_t)s3 * 128 + hl * 4);
        fp8x4_add(u0, a); fp8x4_add(u1, a); fp8x4_add(u2, a); fp8x4_add(u3, a);
    }
    for (; j + 1 < end; j += 2) {
        int s0 = csr[j + half];
        unsigned int u0 = *(const unsigned int*)(t8 + (size_t)s0 * 128 + hl * 4);
        fp8x4_add(u0, a);
    }
    if (j < end && half == 0) {
        int s0 = csr[j];
        unsigned int u0 = *(const unsigned int*)(t8 + (size_t)s0 * 128 + hl * 4);
        fp8x4_add(u0, a);
    }
#pragma unroll
    for (int i = 0; i < 4; i++) a[i] += __shfl_down(a[i], 32);
    if (half == 0) {
        float self[4] = {0, 0, 0, 0};
        fp8x4_add(uh, self);
        float4 bv = ((const float4*)bias)[hl];
        float r0 = fmaxf((a[0] + self[0]) * dd + bv.x, 0.f);
        float r1 = fmaxf((a[1] + self[1]) * dd + bv.y, 0.f);
        float r2 = fmaxf((a[2] + self[2]) * dd + bv.z, 0.f);
        float r3 = fmaxf((a[3] + self[3]) * dd + bv.w, 0.f);
        ((unsigned int*)(out2 + (size_t)node * 128))[hl] = pk4fp8(r0, r1, r2, r3);
    }
}

// ---------------- pool (8 slices/graph, atomic flush) + per-graph last-slice head ----------------
__global__ __launch_bounds__(256) void poolhead_kernel(const unsigned char* __restrict__ out2,
                                                       const int* __restrict__ gstart,
                                                       float* __restrict__ gsum,
                                                       int* __restrict__ gdone,
                                                       const float* __restrict__ Wl1,
                                                       const float* __restrict__ bl1,
                                                       const float* __restrict__ Wl2,
                                                       const float* __restrict__ bl2,
                                                       float* __restrict__ out) {
    int g = blockIdx.x >> 3, slice = blockIdx.x & 7;
    int tid = threadIdx.x;
    int hw = tid >> 5, hl = tid & 31;
    int gs = gstart[g], ge = gstart[g + 1];
    float a[4] = {0, 0, 0, 0};
    for (int i = gs + slice * 8 + hw; i < ge; i += 64) {
        unsigned int u = ((const unsigned int*)(out2 + (size_t)i * 128))[hl];
        fp8x4_add(u, a);
    }
    __shared__ float red[8][128];
#pragma unroll
    for (int k = 0; k < 4; k++) red[hw][hl * 4 + k] = a[k];
    __syncthreads();
    if (tid < 128) {
        float s = 0.f;
#pragma unroll
        for (int w = 0; w < 8; w++) s += red[w][tid];
        if (s != 0.f) atomicAdd(&gsum[g * 128 + tid], s);
    }
    __syncthreads();
    __shared__ int lastflag;
    if (tid == 0) {
        __threadfence();
        int old = atomicAdd(&gdone[g], 1);
        lastflag = (old == 7) ? 1 : 0;
    }
    __syncthreads();
    if (!lastflag) return;
    __shared__ float gv[128];
    if (tid < 128) {
        float s = atomicAdd(&gsum[g * 128 + tid], 0.0f);
        float cntf = fmaxf((float)(ge - gs), 1.0f);
        gv[tid] = s / cntf;
    }
    __syncthreads();
    if (tid < 64) {
        float acc = bl1[tid];
#pragma unroll 8
        for (int k = 0; k < 128; k++) acc += gv[k] * Wl1[k * 64 + tid];
        acc = fmaxf(acc, 0.f);
        float p = acc * Wl2[tid];
#pragma unroll
        for (int off = 32; off; off >>= 1) p += __shfl_down(p, off);
        if (tid == 0) out[g] = 1.f / (1.f + expf(-(p + bl2[0])));
    }
}

extern "C" void kernel_launch(void* const* d_in, const int* in_sizes, int n_in,
                              void* d_out, int out_size, void* d_ws, size_t ws_size,
                              hipStream_t stream) {
    const float* x   = (const float*)d_in[0];
    const int* ei    = (const int*)d_in[1];
    const int* batch = (const int*)d_in[2];
    const float* W1  = (const float*)d_in[3];
    const float* b1  = (const float*)d_in[4];
    const float* W2  = (const float*)d_in[5];
    const float* b2  = (const float*)d_in[6];
    const float* Wl1 = (const float*)d_in[7];
    const float* bl1 = (const float*)d_in[8];
    const float* Wl2 = (const float*)d_in[9];
    const float* bl2 = (const float*)d_in[10];
    float* out = (float*)d_out;

    const int N = in_sizes[2];         // 20000
    const int E = in_sizes[1] / 2;     // 320000
    const int G = 64;
    const int* src = ei;
    const int* dst = ei + E;

    char* base = (char*)d_ws;
    size_t off = 0;
    auto carve = [&](size_t bytes) -> char* {
        char* p = base + off;
        off = (off + bytes + 15) & ~(size_t)15;
        return p;
    };
    int*   cnt    = (int*)carve((size_t)N * 4);
    float* gsum   = (float*)carve((size_t)G * 128 * 4);
    int*   gdone  = (int*)carve((size_t)G * 4);
    size_t zero_bytes = (size_t)(N + G * 128 + G) * 4 + 32;
    int*   csr    = (int*)carve((size_t)N * 64 * 4);
    int*   gstart = (int*)carve((size_t)(G + 1) * 4);
    unsigned short* w1t  = (unsigned short*)carve((size_t)256 * 256 * 2);
    unsigned char*  w2t8 = (unsigned char*)carve((size_t)128 * 256);
    unsigned char*  h8   = (unsigned char*)carve((size_t)N * 256);      // 5.12 MB
    unsigned char*  t8   = (unsigned char*)carve((size_t)N * 128);      // 2.56 MB (no alias: fused kernel reads h8 while writing t8)
    unsigned char*  out2 = (unsigned char*)carve((size_t)N * 128);      // 2.56 MB

    hipMemsetAsync(d_ws, 0, zero_bytes, stream);

    // prep + CSR fill (cnt final after this kernel)
    const int BNB = (N + 255) / 256;                           // 79
    const int CWB = (256 * 256 + 128 * 256 + 255) / 256;       // 384
    const int FB  = (E / 4 + 255) / 256;                       // 313
    prepfill_kernel<<<FB + CWB + BNB, 256, 0, stream>>>(src, dst, cnt, csr, batch, gstart,
                                                        W1, w1t, W2, w2t8, N, G, E, FB, CWB);

    // layer-1 GEMM (f32 A direct): h8 = fp8(dinv(row) * (x @ W1))
    const int GB1 = 2 * ((N + 127) / 128);                     // 314
    gemm1_kernel<<<GB1, 256, 0, stream>>>(x, w1t, cnt, h8, N);

    // FUSED: gather256 (o1 in LDS) + layer-2 GEMM: t8 = fp8(dinv(row) * (o1 @ W2))
    l1agg_gemm2_kernel<<<(N + 63) / 64, 512, 0, stream>>>(h8, csr, cnt, b1, w2t8, t8, N);

    gather128_kernel<<<(N + 3) / 4, 256, 0, stream>>>(t8, csr, cnt, b2, out2, N);

    // pool + head fused (per-graph last-slice head)
    poolhead_kernel<<<G * 8, 256, 0, stream>>>(out2, gstart, gsum, gdone,
                                               Wl1, bl1, Wl2, bl2, out);
}

// Round 6
// 170.986 us; speedup vs baseline: 1.0201x; 1.0201x over previous
//
#include <hip/hip_runtime.h>
#include <hip/hip_bf16.h>
#include <math.h>

typedef __attribute__((ext_vector_type(8))) short bf16x8;
typedef __attribute__((ext_vector_type(4))) float f32x4;

__device__ __forceinline__ unsigned short f2bf(float f) {
    unsigned int u = __float_as_uint(f);
    unsigned int r = (u + 0x7FFFu + ((u >> 16) & 1u)) >> 16;
    return (unsigned short)r;
}
__device__ __forceinline__ unsigned int pk2bf(float lo, float hi) {
    unsigned int r;
    asm("v_cvt_pk_bf16_f32 %0, %1, %2" : "=v"(r) : "v"(lo), "v"(hi));
    return r;
}
__device__ __forceinline__ unsigned char f2fp8(float v) {
    int p = __builtin_amdgcn_cvt_pk_fp8_f32(v, v, 0, false);
    return (unsigned char)(p & 0xff);
}
__device__ __forceinline__ unsigned int pk4fp8(float a, float b, float c, float d) {
    int p = __builtin_amdgcn_cvt_pk_fp8_f32(a, b, 0, false);
    p = __builtin_amdgcn_cvt_pk_fp8_f32(c, d, p, true);
    return (unsigned int)p;
}
__device__ __forceinline__ void fp8x8_fma(uint2 u, float w, float* a) {
    a[0] += __builtin_amdgcn_cvt_f32_fp8((int)u.x, 0) * w;
    a[1] += __builtin_amdgcn_cvt_f32_fp8((int)u.x, 1) * w;
    a[2] += __builtin_amdgcn_cvt_f32_fp8((int)u.x, 2) * w;
    a[3] += __builtin_amdgcn_cvt_f32_fp8((int)u.x, 3) * w;
    a[4] += __builtin_amdgcn_cvt_f32_fp8((int)u.y, 0) * w;
    a[5] += __builtin_amdgcn_cvt_f32_fp8((int)u.y, 1) * w;
    a[6] += __builtin_amdgcn_cvt_f32_fp8((int)u.y, 2) * w;
    a[7] += __builtin_amdgcn_cvt_f32_fp8((int)u.y, 3) * w;
}
__device__ __forceinline__ void fp8x4_fma(unsigned int u, float w, float* a) {
    a[0] += __builtin_amdgcn_cvt_f32_fp8((int)u, 0) * w;
    a[1] += __builtin_amdgcn_cvt_f32_fp8((int)u, 1) * w;
    a[2] += __builtin_amdgcn_cvt_f32_fp8((int)u, 2) * w;
    a[3] += __builtin_amdgcn_cvt_f32_fp8((int)u, 3) * w;
}
__device__ __forceinline__ float deg_dinv(int c) { return rsqrtf((float)c + 1.0f); }

__device__ __forceinline__ void load_lds16(const unsigned short* g, unsigned short* l) {
    __builtin_amdgcn_global_load_lds(
        (const __attribute__((address_space(1))) unsigned int*)g,
        (__attribute__((address_space(3))) unsigned int*)l, 16, 0, 0);
}
__device__ __forceinline__ void load_lds16_u8(const unsigned char* g, unsigned char* l) {
    __builtin_amdgcn_global_load_lds(
        (const __attribute__((address_space(1))) unsigned int*)g,
        (__attribute__((address_space(3))) unsigned int*)l, 16, 0, 0);
}

// ============ prep: graph bounds | W1 -> bf16^T | W2 -> fp8^T ============
__global__ __launch_bounds__(256) void prep_kernel(const int* __restrict__ batch,
                                                   int* __restrict__ gstart,
                                                   const float* __restrict__ W1,
                                                   unsigned short* __restrict__ w1t,
                                                   const float* __restrict__ W2,
                                                   unsigned char* __restrict__ w2t8,
                                                   int N, int G, int BNB) {
    int b = blockIdx.x;
    int tid = threadIdx.x;
    if (b < BNB) {
        int i = b * 256 + tid;
        if (i >= N) return;
        int bb = batch[i];
        if (i == 0) { for (int g = 0; g <= bb; g++) gstart[g] = 0; }
        else { int bp = batch[i - 1]; for (int g = bp + 1; g <= bb; g++) gstart[g] = i; }
        if (i == N - 1) { for (int g = bb + 1; g <= G; g++) gstart[g] = N; }
        return;
    }
    int idx = (b - BNB) * 256 + tid;
    if (idx < 256 * 256) {
        int m = idx >> 8, k = idx & 255;
        w1t[idx] = f2bf(W1[(size_t)k * 256 + m]);
    } else if (idx < 256 * 256 + 128 * 256) {
        int j = idx - 256 * 256;
        int m = j >> 8, k = j & 255;
        w2t8[j] = f2fp8(W2[(size_t)k * 128 + m]);
    }
}

// ---------------- merged: CSR fill + layer-1 GEMM (f32 A direct, 128x128 tile) ----------------
__global__ __launch_bounds__(256) void fill_gemm1_kernel(const int* __restrict__ src,
                                                         const int* __restrict__ dst,
                                                         int* __restrict__ cnt,
                                                         int* __restrict__ csr,
                                                         const float* __restrict__ x,
                                                         const unsigned short* __restrict__ Bt,
                                                         unsigned char* __restrict__ C8,
                                                         int N, int E, int FB) {
    __shared__ unsigned short As[128 * 32];   // 8 KB, swizzled chunks
    __shared__ unsigned short Bs[128 * 32];   // 8 KB, linear
    if ((int)blockIdx.x < FB) {
        int e = (blockIdx.x * 256 + threadIdx.x) * 4;
        if (e + 3 < E) {
            int4 d4 = *(const int4*)(dst + e);
            int4 s4 = *(const int4*)(src + e);
            int sl;
            sl = atomicAdd(&cnt[d4.x], 1); if (sl < 64) csr[(d4.x << 6) + sl] = s4.x;
            sl = atomicAdd(&cnt[d4.y], 1); if (sl < 64) csr[(d4.y << 6) + sl] = s4.y;
            sl = atomicAdd(&cnt[d4.z], 1); if (sl < 64) csr[(d4.z << 6) + sl] = s4.z;
            sl = atomicAdd(&cnt[d4.w], 1); if (sl < 64) csr[(d4.w << 6) + sl] = s4.w;
        } else {
            for (; e < E; e++) {
                int d = dst[e];
                int slot = atomicAdd(&cnt[d], 1);
                if (slot < 64) csr[(d << 6) + slot] = src[e];
            }
        }
        return;
    }
    int gb = blockIdx.x - FB;
    int bx = gb & 1, by = gb >> 1;
    const int K = 256;
    int tid = threadIdx.x;
    int wave = tid >> 6, lane = tid & 63;
    int quad = lane >> 4, m16 = lane & 15;
    int r0 = by * 128, c0 = bx * 128;
    int srow = lane >> 2;
    int skoff = (lane & 3) * 8;

    f32x4 acc[2][8];
#pragma unroll
    for (int rg = 0; rg < 2; rg++)
#pragma unroll
        for (int ct = 0; ct < 8; ct++) acc[rg][ct] = (f32x4){0.f, 0.f, 0.f, 0.f};

    // reg-staged A (f32 -> bf16 via v_cvt_pk), XOR-swizzled 16B-chunk layout:
    // LDS chunk c' holds global chunk c' ^ ((row>>1)&3)
    int arow = tid >> 1, akh = tid & 1;
    int agrow = r0 + arow; if (agrow >= N) agrow = N - 1;
    const float* ap = x + (size_t)agrow * K + akh * 16;
    int asw = (arow >> 1) & 3;
    unsigned short* as0 = As + arow * 32 + ((((akh << 1) | 0) ^ asw) << 3);
    unsigned short* as1 = As + arow * 32 + ((((akh << 1) | 1) ^ asw) << 3);
    int rsw = (m16 >> 1) & 3;

    for (int kb = 0; kb < K; kb += 32) {
        float4 f0 = *(const float4*)(ap + kb);
        float4 f1 = *(const float4*)(ap + kb + 4);
        float4 f2 = *(const float4*)(ap + kb + 8);
        float4 f3 = *(const float4*)(ap + kb + 12);
        {
            int bcol = wave * 16 + srow;
            load_lds16(Bt + (size_t)(c0 + bcol) * K + kb + skoff, Bs + (wave * 16) * 32);
            load_lds16(Bt + (size_t)(c0 + 64 + bcol) * K + kb + skoff, Bs + (64 + wave * 16) * 32);
        }
        uint4 u0, u1;
        u0.x = pk2bf(f0.x, f0.y); u0.y = pk2bf(f0.z, f0.w);
        u0.z = pk2bf(f1.x, f1.y); u0.w = pk2bf(f1.z, f1.w);
        u1.x = pk2bf(f2.x, f2.y); u1.y = pk2bf(f2.z, f2.w);
        u1.z = pk2bf(f3.x, f3.y); u1.w = pk2bf(f3.z, f3.w);
        *(uint4*)as0 = u0;
        *(uint4*)as1 = u1;
        __syncthreads();
        bf16x8 af[2], bfr[8];
#pragma unroll
        for (int rg = 0; rg < 2; rg++)
            af[rg] = *(const bf16x8*)(As + (wave * 32 + rg * 16 + m16) * 32 + ((quad ^ rsw) << 3));
#pragma unroll
        for (int ct = 0; ct < 8; ct++)
            bfr[ct] = *(const bf16x8*)(Bs + (ct * 16 + m16) * 32 + (quad << 3));
#pragma unroll
        for (int rg = 0; rg < 2; rg++)
#pragma unroll
            for (int ct = 0; ct < 8; ct++)
                acc[rg][ct] = __builtin_amdgcn_mfma_f32_16x16x32_bf16(af[rg], bfr[ct], acc[rg][ct], 0, 0, 0);
        __syncthreads();
    }
#pragma unroll
    for (int rg = 0; rg < 2; rg++) {
#pragma unroll
        for (int ct = 0; ct < 8; ct++) {
            int col = c0 + ct * 16 + m16;
#pragma unroll
            for (int r = 0; r < 4; r++) {
                int row = r0 + wave * 32 + rg * 16 + quad * 4 + r;
                if (row < N) C8[(size_t)row * 256 + col] = f2fp8(acc[rg][ct][r]);
            }
        }
    }
}

// ---------------- layer-2 GEMM: fp8 x fp8 -> fp8 (128x64 tile) ----------------
__global__ __launch_bounds__(256) void gemm2_kernel(const unsigned char* __restrict__ A,
                                                    const unsigned char* __restrict__ Bt,
                                                    unsigned char* __restrict__ C8, int N) {
    __shared__ unsigned char As8[128 * 32];   // 4 KB
    __shared__ unsigned char Bs8[64 * 32];    // 2 KB
    const int K = 256;
    int tid = threadIdx.x;
    int wave = tid >> 6, lane = tid & 63;
    int quad = lane >> 4, m16 = lane & 15;
    int bx = blockIdx.x, by = blockIdx.y;
    int r0 = by * 128, c0 = bx * 64;

    f32x4 acc[2][4];
#pragma unroll
    for (int rg = 0; rg < 2; rg++)
#pragma unroll
        for (int ct = 0; ct < 4; ct++) acc[rg][ct] = (f32x4){0.f, 0.f, 0.f, 0.f};

    int arow = wave * 32 + (lane >> 1);
    int agrow = r0 + arow; if (agrow >= N) agrow = N - 1;
    int ach = (lane & 1) * 16;
    int brow = (wave & 1) * 32 + (lane >> 1);   // waves 0,1 load B rows 0..63
    int bch = (lane & 1) * 16;

    for (int kb = 0; kb < K; kb += 32) {
        load_lds16_u8(A + (size_t)agrow * K + kb + ach, As8 + (wave * 32) * 32);
        if (wave < 2)
            load_lds16_u8(Bt + (size_t)(c0 + brow) * K + kb + bch, Bs8 + (wave * 32) * 32);
        __syncthreads();
        long af[2], bfr[4];
#pragma unroll
        for (int rg = 0; rg < 2; rg++)
            af[rg] = *(const long*)(As8 + (wave * 32 + rg * 16 + m16) * 32 + (quad << 3));
#pragma unroll
        for (int ct = 0; ct < 4; ct++)
            bfr[ct] = *(const long*)(Bs8 + (ct * 16 + m16) * 32 + (quad << 3));
#pragma unroll
        for (int rg = 0; rg < 2; rg++)
#pragma unroll
            for (int ct = 0; ct < 4; ct++)
                acc[rg][ct] = __builtin_amdgcn_mfma_f32_16x16x32_fp8_fp8(af[rg], bfr[ct], acc[rg][ct], 0, 0, 0);
        __syncthreads();
    }
#pragma unroll
    for (int rg = 0; rg < 2; rg++) {
#pragma unroll
        for (int ct = 0; ct < 4; ct++) {
            int col = c0 + ct * 16 + m16;
#pragma unroll
            for (int r = 0; r < 4; r++) {
                int row = r0 + wave * 32 + rg * 16 + quad * 4 + r;
                if (row < N) C8[(size_t)row * 128 + col] = f2fp8(acc[rg][ct][r]);
            }
        }
    }
}

// ---------------- gather 256 ch, fp8 in, fp8 out ----------------
__global__ __launch_bounds__(256) void gather256_kernel(const unsigned char* __restrict__ h8,
                                                        const int* __restrict__ csr,
                                                        const int* __restrict__ cnt,
                                                        const float* __restrict__ bias,
                                                        unsigned char* __restrict__ o18, int N) {
    int node = blockIdx.x * 4 + (threadIdx.x >> 6);
    if (node >= N) return;
    int lane = threadIdx.x & 63;
    int half = lane >> 5, hl = lane & 31;
    int beg = node << 6;
    int c = cnt[node]; if (c > 64) c = 64;
    int end = beg + c;
    float a[8] = {0, 0, 0, 0, 0, 0, 0, 0};
    int j = beg;
    for (; j + 7 < end; j += 8) {
        int s0 = csr[j + half], s1 = csr[j + 2 + half];
        int s2 = csr[j + 4 + half], s3 = csr[j + 6 + half];
        float w0 = deg_dinv(cnt[s0]), w1 = deg_dinv(cnt[s1]);
        float w2 = deg_dinv(cnt[s2]), w3 = deg_dinv(cnt[s3]);
        uint2 u0 = *(const uint2*)(h8 + (size_t)s0 * 256 + hl * 8);
        uint2 u1 = *(const uint2*)(h8 + (size_t)s1 * 256 + hl * 8);
        uint2 u2 = *(const uint2*)(h8 + (size_t)s2 * 256 + hl * 8);
        uint2 u3 = *(const uint2*)(h8 + (size_t)s3 * 256 + hl * 8);
        fp8x8_fma(u0, w0, a); fp8x8_fma(u1, w1, a);
        fp8x8_fma(u2, w2, a); fp8x8_fma(u3, w3, a);
    }
    for (; j + 1 < end; j += 2) {
        int s0 = csr[j + half];
        float w0 = deg_dinv(cnt[s0]);
        uint2 u0 = *(const uint2*)(h8 + (size_t)s0 * 256 + hl * 8);
        fp8x8_fma(u0, w0, a);
    }
    if (j < end && half == 0) {
        int s0 = csr[j];
        float w0 = deg_dinv(cnt[s0]);
        uint2 u0 = *(const uint2*)(h8 + (size_t)s0 * 256 + hl * 8);
        fp8x8_fma(u0, w0, a);
    }
#pragma unroll
    for (int i = 0; i < 8; i++) a[i] += __shfl_down(a[i], 32);
    if (half == 0) {
        float dd = deg_dinv(c);
        float self[8] = {0, 0, 0, 0, 0, 0, 0, 0};
        uint2 uh = *(const uint2*)(h8 + (size_t)node * 256 + hl * 8);
        fp8x8_fma(uh, dd, self);
        float4 bv0 = ((const float4*)bias)[hl * 2];
        float4 bv1 = ((const float4*)bias)[hl * 2 + 1];
        float bvf[8] = {bv0.x, bv0.y, bv0.z, bv0.w, bv1.x, bv1.y, bv1.z, bv1.w};
        float v[8];
#pragma unroll
        for (int i = 0; i < 8; i++) v[i] = fmaxf((a[i] + self[i]) * dd + bvf[i], 0.f);
        uint2 o;
        o.x = pk4fp8(v[0], v[1], v[2], v[3]);
        o.y = pk4fp8(v[4], v[5], v[6], v[7]);
        ((uint2*)(o18 + (size_t)node * 256))[hl] = o;
    }
}

// ---------------- gather 128 ch, fp8 in, fp8 out ----------------
__global__ __launch_bounds__(256) void gather128_kernel(const unsigned char* __restrict__ t8,
                                                        const int* __restrict__ csr,
                                                        const int* __restrict__ cnt,
                                                        const float* __restrict__ bias,
                                                        unsigned char* __restrict__ out2, int N) {
    int node = blockIdx.x * 4 + (threadIdx.x >> 6);
    if (node >= N) return;
    int lane = threadIdx.x & 63;
    int half = lane >> 5, hl = lane & 31;
    int beg = node << 6;
    int c = cnt[node]; if (c > 64) c = 64;
    int end = beg + c;
    float a[4] = {0, 0, 0, 0};
    int j = beg;
    for (; j + 7 < end; j += 8) {
        int s0 = csr[j + half], s1 = csr[j + 2 + half];
        int s2 = csr[j + 4 + half], s3 = csr[j + 6 + half];
        float w0 = deg_dinv(cnt[s0]), w1 = deg_dinv(cnt[s1]);
        float w2 = deg_dinv(cnt[s2]), w3 = deg_dinv(cnt[s3]);
        unsigned int u0 = *(const unsigned int*)(t8 + (size_t)s0 * 128 + hl * 4);
        unsigned int u1 = *(const unsigned int*)(t8 + (size_t)s1 * 128 + hl * 4);
        unsigned int u2 = *(const unsigned int*)(t8 + (size_t)s2 * 128 + hl * 4);
        unsigned int u3 = *(const unsigned int*)(t8 + (size_t)s3 * 128 + hl * 4);
        fp8x4_fma(u0, w0, a); fp8x4_fma(u1, w1, a);
        fp8x4_fma(u2, w2, a); fp8x4_fma(u3, w3, a);
    }
    for (; j + 1 < end; j += 2) {
        int s0 = csr[j + half];
        float w0 = deg_dinv(cnt[s0]);
        unsigned int u0 = *(const unsigned int*)(t8 + (size_t)s0 * 128 + hl * 4);
        fp8x4_fma(u0, w0, a);
    }
    if (j < end && half == 0) {
        int s0 = csr[j];
        float w0 = deg_dinv(cnt[s0]);
        unsigned int u0 = *(const unsigned int*)(t8 + (size_t)s0 * 128 + hl * 4);
        fp8x4_fma(u0, w0, a);
    }
#pragma unroll
    for (int i = 0; i < 4; i++) a[i] += __shfl_down(a[i], 32);
    if (half == 0) {
        float dd = deg_dinv(c);
        float self[4] = {0, 0, 0, 0};
        unsigned int uh = *(const unsigned int*)(t8 + (size_t)node * 128 + hl * 4);
        fp8x4_fma(uh, dd, self);
        float4 bv = ((const float4*)bias)[hl];
        float r0 = fmaxf((a[0] + self[0]) * dd + bv.x, 0.f);
        float r1 = fmaxf((a[1] + self[1]) * dd + bv.y, 0.f);
        float r2 = fmaxf((a[2] + self[2]) * dd + bv.z, 0.f);
        float r3 = fmaxf((a[3] + self[3]) * dd + bv.w, 0.f);
        ((unsigned int*)(out2 + (size_t)node * 128))[hl] = pk4fp8(r0, r1, r2, r3);
    }
}

// ---------------- pool (8 slices/graph, atomic flush) + per-graph last-slice head ----------------
__global__ __launch_bounds__(256) void poolhead_kernel(const unsigned char* __restrict__ out2,
                                                       const int* __restrict__ gstart,
                                                       float* __restrict__ gsum,
                                                       int* __restrict__ gdone,
                                                       const float* __restrict__ Wl1,
                                                       const float* __restrict__ bl1,
                                                       const float* __restrict__ Wl2,
                                                       const float* __restrict__ bl2,
                                                       float* __restrict__ out) {
    int g = blockIdx.x >> 3, slice = blockIdx.x & 7;
    int tid = threadIdx.x;
    int hw = tid >> 5, hl = tid & 31;          // 8 half-waves; each reads one row/iter
    int gs = gstart[g], ge = gstart[g + 1];
    float a[4] = {0, 0, 0, 0};
    for (int i = gs + slice * 8 + hw; i < ge; i += 64) {
        unsigned int u = ((const unsigned int*)(out2 + (size_t)i * 128))[hl];
        fp8x4_fma(u, 1.0f, a);
    }
    __shared__ float red[8][128];
#pragma unroll
    for (int k = 0; k < 4; k++) red[hw][hl * 4 + k] = a[k];
    __syncthreads();
    if (tid < 128) {
        float s = 0.f;
#pragma unroll
        for (int w = 0; w < 8; w++) s += red[w][tid];
        if (s != 0.f) atomicAdd(&gsum[g * 128 + tid], s);
    }
    // make this block's atomics globally visible, then count in
    __syncthreads();
    __shared__ int lastflag;
    if (tid == 0) {
        __threadfence();
        int old = atomicAdd(&gdone[g], 1);
        lastflag = (old == 7) ? 1 : 0;
    }
    __syncthreads();
    if (!lastflag) return;
    // last slice for graph g: compute head
    __shared__ float gv[128];
    if (tid < 128) {
        float s = atomicAdd(&gsum[g * 128 + tid], 0.0f);   // coherent read
        float cntf = fmaxf((float)(ge - gs), 1.0f);
        gv[tid] = s / cntf;
    }
    __syncthreads();
    if (tid < 64) {
        float acc = bl1[tid];
#pragma unroll 8
        for (int k = 0; k < 128; k++) acc += gv[k] * Wl1[k * 64 + tid];
        acc = fmaxf(acc, 0.f);
        float p = acc * Wl2[tid];
#pragma unroll
        for (int off = 32; off; off >>= 1) p += __shfl_down(p, off);
        if (tid == 0) out[g] = 1.f / (1.f + expf(-(p + bl2[0])));
    }
}

extern "C" void kernel_launch(void* const* d_in, const int* in_sizes, int n_in,
                              void* d_out, int out_size, void* d_ws, size_t ws_size,
                              hipStream_t stream) {
    const float* x   = (const float*)d_in[0];
    const int* ei    = (const int*)d_in[1];
    const int* batch = (const int*)d_in[2];
    const float* W1  = (const float*)d_in[3];
    const float* b1  = (const float*)d_in[4];
    const float* W2  = (const float*)d_in[5];
    const float* b2  = (const float*)d_in[6];
    const float* Wl1 = (const float*)d_in[7];
    const float* bl1 = (const float*)d_in[8];
    const float* Wl2 = (const float*)d_in[9];
    const float* bl2 = (const float*)d_in[10];
    float* out = (float*)d_out;

    const int N = in_sizes[2];         // 20000
    const int E = in_sizes[1] / 2;     // 320000
    const int G = 64;
    const int* src = ei;
    const int* dst = ei + E;

    // ---- workspace carve (zeroed region first: cnt, gsum, gdone) ----
    char* base = (char*)d_ws;
    size_t off = 0;
    auto carve = [&](size_t bytes) -> char* {
        char* p = base + off;
        off = (off + bytes + 15) & ~(size_t)15;
        return p;
    };
    int*   cnt    = (int*)carve((size_t)N * 4);
    float* gsum   = (float*)carve((size_t)G * 128 * 4);
    int*   gdone  = (int*)carve((size_t)G * 4);
    size_t zero_bytes = (size_t)(N + G * 128 + G) * 4 + 32;
    int*   csr    = (int*)carve((size_t)N * 64 * 4);
    int*   gstart = (int*)carve((size_t)(G + 1) * 4);
    unsigned short* w1t  = (unsigned short*)carve((size_t)256 * 256 * 2);
    unsigned char*  w2t8 = (unsigned char*)carve((size_t)128 * 256);
    unsigned char*  h8   = (unsigned char*)carve((size_t)N * 256);      // 5.12 MB
    unsigned char*  o18  = (unsigned char*)carve((size_t)N * 256);      // 5.12 MB
    // lifetime-disjoint aliases:
    unsigned char*  t8   = h8;    // [N][128] fp8; h8 dead after gather256
    unsigned char*  out2 = o18;   // [N][128] fp8; o18 dead after gemm2

    hipMemsetAsync(d_ws, 0, zero_bytes, stream);

    // prep: bounds | weight conversion
    const int BNB = (N + 255) / 256;                           // 79
    const int CWB = (256 * 256 + 128 * 256 + 255) / 256;       // 384
    prep_kernel<<<BNB + CWB, 256, 0, stream>>>(batch, gstart, W1, w1t, W2, w2t8, N, G, BNB);

    // merged CSR fill + layer-1 GEMM (f32 A direct): h8 = fp8(x @ W1)
    const int FB  = (E / 4 + 255) / 256;                       // 313
    const int GB1 = 2 * ((N + 127) / 128);                     // 314
    fill_gemm1_kernel<<<FB + GB1, 256, 0, stream>>>(src, dst, cnt, csr,
                                                    x, w1t, h8, N, E, FB);

    gather256_kernel<<<(N + 3) / 4, 256, 0, stream>>>(h8, csr, cnt, b1, o18, N);

    // layer 2 (fp8 x fp8): t8 = fp8(o18 @ W2)
    {
        dim3 grid(2, (N + 127) / 128);
        gemm2_kernel<<<grid, 256, 0, stream>>>(o18, w2t8, t8, N);
    }
    gather128_kernel<<<(N + 3) / 4, 256, 0, stream>>>(t8, csr, cnt, b2, out2, N);

    // pool + head fused (per-graph last-slice head)
    poolhead_kernel<<<G * 8, 256, 0, stream>>>(out2, gstart, gsum, gdone,
                                               Wl1, bl1, Wl2, bl2, out);
}